// Round 2
// baseline (300.091 us; speedup 1.0000x reference)
//
#include <hip/hip_runtime.h>
#include <math.h>

// NT=64, NR=4, DK=2, KU=8, BR=16, BATCH=256
// channel:    [B][64][4][16][16] f32 (last dim: 8 re, 8 im)
// prediction: [B][2560] = U[4][2][16][16] ++ W[2][2][16][8]
// out:        [B][64][2][8][2] f32

#define SAUG 84   // float2 stride of Aug rows; 84 % 16 == 4 -> even bank-pair spread
#define ST   65   // float2 stride of transposed Tt/Ht rows; (m+t) mod 16 spread
#define USTR 260  // float2 stride per r-slice of U; 260 % 16 == 4

namespace {
union ShU {
    struct { float2 Tt[2][16][ST]; float2 Ht[2][16][ST]; } p1;  // 33280 B
    float2 Aug[64][SAUG];                                       // 43008 B
};
union ShV {
    struct { float2 U[4 * USTR]; float W[512]; } in;            // 18688 B
    float2 xout[64][17];                                        // 8704 B
};
}

__device__ __forceinline__ float2 cmul(float2 x, float2 y) {
    return make_float2(x.x * y.x - x.y * y.y, x.x * y.y + x.y * y.x);
}

__global__ __launch_bounds__(256, 1)
void uw2v_kernel(const float* __restrict__ channel,
                 const float* __restrict__ prediction,
                 float2* __restrict__ out)
{
    __shared__ ShU sh;
    __shared__ ShV sv;
    __shared__ float2 redbuf[4];
    __shared__ float  fred[4];
    __shared__ float  cmag[2][4];
    __shared__ int    cidx[2][4];

    const int b   = blockIdx.x;
    const int tid = threadIdx.x;
    const int wv  = tid >> 6;
    const float* pred = prediction + (size_t)b * 2560;
    const float* chan = channel + (size_t)b * 65536;

    // ---- load U (padded stride per r), W ----
    #pragma unroll
    for (int i = 0; i < 4; ++i) {
        int m = tid + i * 256;                       // [r][d][f][k]
        int r = m >> 8, d = (m >> 7) & 1, f = (m >> 3) & 15, k = m & 7;
        const float* src = pred + (((r * 2 + d) * 16 + f) << 4);
        sv.in.U[r * USTR + ((d * 16 + f) << 3) + k] = make_float2(src[k], src[k + 8]);
    }
    sv.in.W[tid]       = pred[2048 + tid];
    sv.in.W[tid + 256] = pred[2304 + tid];
    __syncthreads();

    const int t4 = tid >> 2, r4 = tid & 3;     // HHU: row t4, reduce over r4
    const int a  = tid >> 4, bb = tid & 15;    // quad: rows a+16i, cols bb+16j

    float2 qacc[4][4];
    #pragma unroll
    for (int i = 0; i < 4; ++i)
        #pragma unroll
        for (int j = 0; j < 4; ++j) qacc[i][j] = make_float2(0.f, 0.f);
    float2 huw[4] = {make_float2(0,0), make_float2(0,0), make_float2(0,0), make_float2(0,0)};
    float2 tracc  = make_float2(0.f, 0.f);

    const float* hbase = chan + ((t4 * 4 + r4) << 8);   // 16 f x 16 floats
    float4 h0 = *(const float4*)(hbase + 0);
    float4 h1 = *(const float4*)(hbase + 4);
    float4 h2 = *(const float4*)(hbase + 8);
    float4 h3 = *(const float4*)(hbase + 12);

    #pragma unroll 1
    for (int f = 0; f < 16; ++f) {
        float4 ca = h0, cb = h1, ci = h2, cd = h3;
        if (f < 15) {                                    // prefetch next f
            const float* nb = hbase + ((f + 1) << 4);
            h0 = *(const float4*)(nb + 0);
            h1 = *(const float4*)(nb + 4);
            h2 = *(const float4*)(nb + 8);
            h3 = *(const float4*)(nb + 12);
        }
        const float hre[8] = {ca.x, ca.y, ca.z, ca.w, cb.x, cb.y, cb.z, cb.w};
        const float him[8] = {ci.x, ci.y, ci.z, ci.w, cd.x, cd.y, cd.z, cd.w};

        // HHU[t4][m] = sum_r conj(H)*U : butterfly over 4-lane r-group
        float2 hh[16];
        #pragma unroll
        for (int d = 0; d < 2; ++d)
            #pragma unroll
            for (int k = 0; k < 8; ++k) {
                float2 u = sv.in.U[r4 * USTR + ((d * 16 + f) << 3) + k];
                hh[d * 8 + k] = make_float2(hre[k] * u.x + him[k] * u.y,
                                            hre[k] * u.y - him[k] * u.x);
            }
        #pragma unroll
        for (int m = 0; m < 16; ++m) {
            hh[m].x += __shfl_xor(hh[m].x, 1);
            hh[m].y += __shfl_xor(hh[m].y, 1);
            hh[m].x += __shfl_xor(hh[m].x, 2);
            hh[m].y += __shfl_xor(hh[m].y, 2);
        }
        // T[t4][e*8+k] = sum_d HHU[t4][d*8+k] * W[d][e][f][k]  (W real)
        float2 tre[16];
        #pragma unroll
        for (int e = 0; e < 2; ++e)
            #pragma unroll
            for (int k = 0; k < 8; ++k) {
                float w0 = sv.in.W[((0 * 2 + e) * 16 + f) * 8 + k];
                float w1 = sv.in.W[((1 * 2 + e) * 16 + f) * 8 + k];
                tre[e * 8 + k] = make_float2(hh[k].x * w0 + hh[8 + k].x * w1,
                                             hh[k].y * w0 + hh[8 + k].y * w1);
            }
        // HUW accumulate in registers (m slice 4*r4..4*r4+3)
        #pragma unroll
        for (int i = 0; i < 4; ++i) {
            huw[i].x += tre[4 * r4 + i].x;
            huw[i].y += tre[4 * r4 + i].y;
        }
        // tr_UWU partial
        if (tid < 128) {
            int r = tid >> 5, d = (tid >> 4) & 1, e = (tid >> 3) & 1, k = tid & 7;
            float w  = sv.in.W[((d * 2 + e) * 16 + f) * 8 + k];
            float2 u1 = sv.in.U[r * USTR + ((d * 16 + f) << 3) + k];
            float2 u2 = sv.in.U[r * USTR + ((e * 16 + f) << 3) + k];
            tracc.x += w * (u1.x * u2.x + u1.y * u2.y);
            tracc.y += w * (u1.y * u2.x - u1.x * u2.y);
        }
        // write transposed double-buffered tiles (each lane writes its m-slice)
        const int p = f & 1;
        #pragma unroll
        for (int i = 0; i < 4; ++i) {
            int m = 4 * r4 + i;
            sh.p1.Ht[p][m][t4] = hh[m];
            sh.p1.Tt[p][m][t4] = tre[m];
        }
        __syncthreads();

        // quad[t][s] += sum_m T[t][m] * conj(HHU[s][m]) -- conflict-free reads
        #pragma unroll
        for (int m = 0; m < 16; ++m) {
            float2 tv[4], hv[4];
            #pragma unroll
            for (int i = 0; i < 4; ++i) tv[i] = sh.p1.Tt[p][m][a + 16 * i];
            #pragma unroll
            for (int j = 0; j < 4; ++j) hv[j] = sh.p1.Ht[p][m][bb + 16 * j];
            #pragma unroll
            for (int i = 0; i < 4; ++i)
                #pragma unroll
                for (int j = 0; j < 4; ++j) {
                    qacc[i][j].x += tv[i].x * hv[j].x + tv[i].y * hv[j].y;
                    qacc[i][j].y += tv[i].y * hv[j].x - tv[i].x * hv[j].y;
                }
        }
    }

    // ---- reduce tr_UWU; barrier also protects Aug overwrite of Tt/Ht ----
    #pragma unroll
    for (int off = 32; off; off >>= 1) {
        tracc.x += __shfl_xor(tracc.x, off);
        tracc.y += __shfl_xor(tracc.y, off);
    }
    if ((tid & 63) == 0) redbuf[wv] = tracc;
    __syncthreads();
    float2 trv;
    trv.x = 0.1f * (redbuf[0].x + redbuf[1].x + redbuf[2].x + redbuf[3].x);
    trv.y = 0.1f * (redbuf[0].y + redbuf[1].y + redbuf[2].y + redbuf[3].y);

    // ---- build augmented system ----
    #pragma unroll
    for (int i = 0; i < 4; ++i)
        #pragma unroll
        for (int j = 0; j < 4; ++j) {
            float2 v = qacc[i][j];
            int row = a + 16 * i, col = bb + 16 * j;
            if (row == col) { v.x += trv.x; v.y += trv.y; }
            sh.Aug[row][col] = v;
        }
    #pragma unroll
    for (int i = 0; i < 4; ++i)
        sh.Aug[t4][64 + 4 * r4 + i] = huw[i];
    __syncthreads();

    // ---- initial pivot candidates for column 0 ----
    {
        float mag = -1.f;
        if (r4 == 0) {
            float2 v = sh.Aug[t4][0];
            mag = v.x * v.x + v.y * v.y;
        }
        int idx = t4;
        #pragma unroll
        for (int off = 32; off; off >>= 1) {
            float om = __shfl_xor(mag, off);
            int   oi = __shfl_xor(idx, off);
            if (om > mag) { mag = om; idx = oi; }
        }
        if ((tid & 63) == 0) { cmag[0][wv] = mag; cidx[0][wv] = idx; }
    }
    __syncthreads();

    // ---- Gauss-Jordan, virtual pivoting, 1 barrier/step ----
    const int i = t4, c = r4;
    int myks = 0; float2 myipv = make_float2(0.f, 0.f); bool done = false;

    #pragma unroll 1
    for (int ks = 0; ks < 64; ++ks) {
        const int pb = ks & 1;
        float m0 = cmag[pb][0]; int p = cidx[pb][0];
        if (cmag[pb][1] > m0) { m0 = cmag[pb][1]; p = cidx[pb][1]; }
        if (cmag[pb][2] > m0) { m0 = cmag[pb][2]; p = cidx[pb][2]; }
        if (cmag[pb][3] > m0) { m0 = cmag[pb][3]; p = cidx[pb][3]; }

        float2 z = sh.Aug[p][ks];                       // broadcast read
        float  zi = 1.0f / (z.x * z.x + z.y * z.y);
        float2 ipv = make_float2(z.x * zi, -z.y * zi);

        float nmag = -1.f;
        if (i == p) {
            if (!done) { done = true; myks = ks; myipv = ipv; }
        } else {
            float2 ai = sh.Aug[i][ks];
            float2 L  = cmul(ai, ipv);
            int j0 = ks + 1 + ((c - (ks + 1)) & 3);
            for (int j = j0; j < 80; j += 4) {
                float2 pr = sh.Aug[p][j];               // broadcast read
                float2 v  = sh.Aug[i][j];
                v.x -= L.x * pr.x - L.y * pr.y;
                v.y -= L.x * pr.y + L.y * pr.x;
                sh.Aug[i][j] = v;
                if (j == ks + 1 && !done)
                    nmag = v.x * v.x + v.y * v.y;       // lookahead candidate
            }
        }
        int idx = i;
        #pragma unroll
        for (int off = 32; off; off >>= 1) {
            float om = __shfl_xor(nmag, off);
            int   oi = __shfl_xor(idx, off);
            if (om > nmag) { nmag = om; idx = oi; }
        }
        if ((tid & 63) == 0) { cmag[pb ^ 1][wv] = nmag; cidx[pb ^ 1][wv] = idx; }
        __syncthreads();
    }

    // ---- solution, normalization, output ----
    float ss = 0.f;
    #pragma unroll
    for (int cc = 0; cc < 4; ++cc) {
        int j = 64 + c + 4 * cc;
        float2 v  = sh.Aug[i][j];
        float2 xv = cmul(v, myipv);
        ss += xv.x * xv.x + xv.y * xv.y;
        sv.xout[myks][c + 4 * cc] = xv;
    }
    #pragma unroll
    for (int off = 32; off; off >>= 1) ss += __shfl_xor(ss, off);
    if ((tid & 63) == 0) fred[wv] = ss;
    __syncthreads();
    float invn = rsqrtf(fred[0] + fred[1] + fred[2] + fred[3]);
    #pragma unroll
    for (int q = 0; q < 4; ++q) {
        int m = tid + q * 256;
        float2 v = sv.xout[m >> 4][m & 15];
        out[(size_t)b * 1024 + m] = make_float2(v.x * invn, v.y * invn);
    }
}

extern "C" void kernel_launch(void* const* d_in, const int* in_sizes, int n_in,
                              void* d_out, int out_size, void* d_ws, size_t ws_size,
                              hipStream_t stream) {
    const float* channel    = (const float*)d_in[0];
    const float* prediction = (const float*)d_in[1];
    int batch = in_sizes[0] / 65536;   // 256
    uw2v_kernel<<<dim3(batch), dim3(256), 0, stream>>>(channel, prediction,
                                                       (float2*)d_out);
}

// Round 3
// 287.861 us; speedup vs baseline: 1.0425x; 1.0425x over previous
//
#include <hip/hip_runtime.h>
#include <math.h>

// NT=64, NR=4, DK=2, KU=8, BR=16, BATCH=256
// channel:    [B][64][4][16][16] f32 (last dim: 8 re, 8 im)
// prediction: [B][2560] = U[4][2][16][16] ++ W[2][2][16][8]
// out:        [B][64][2][8][2] f32

#define SAUG 84   // float2 stride of Aug rows; 84 % 16 == 4 -> even bank-pair spread
#define ST   66   // float2 stride of transposed Tt/Ht rows; 2-way write aliasing (free)
#define USTR 260  // float2 stride per r-slice of U; 260 % 16 == 4

namespace {
union ShU {
    struct { float2 Tt[2][16][ST]; float2 Ht[2][16][ST]; } p1;  // 33792 B
    float2 Aug[64][SAUG];                                       // 43008 B
};
union ShV {
    struct { float2 U[4 * USTR]; float W[512]; } in;            // 18688 B
    float2 xout[64][17];                                        // 8704 B
};
}

__device__ __forceinline__ float2 cmul(float2 x, float2 y) {
    return make_float2(x.x * y.x - x.y * y.y, x.x * y.y + x.y * y.x);
}

__global__ __launch_bounds__(256, 1)
void uw2v_kernel(const float* __restrict__ channel,
                 const float* __restrict__ prediction,
                 float2* __restrict__ out)
{
    __shared__ ShU sh;
    __shared__ ShV sv;
    __shared__ float2 redbuf[4];
    __shared__ float  fred[4];
    __shared__ float  cmag[2][4];
    __shared__ int    cidx[2][4];

    const int b   = blockIdx.x;
    const int tid = threadIdx.x;
    const int wv  = tid >> 6;
    const float* pred = prediction + (size_t)b * 2560;
    const float* chan = channel + (size_t)b * 65536;

    // ---- load U (padded stride per r), W ----
    #pragma unroll
    for (int i = 0; i < 4; ++i) {
        int m = tid + i * 256;                       // [r][d][f][k]
        int r = m >> 8, d = (m >> 7) & 1, f = (m >> 3) & 15, k = m & 7;
        const float* src = pred + (((r * 2 + d) * 16 + f) << 4);
        sv.in.U[r * USTR + ((d * 16 + f) << 3) + k] = make_float2(src[k], src[k + 8]);
    }
    sv.in.W[tid]       = pred[2048 + tid];
    sv.in.W[tid + 256] = pred[2304 + tid];
    __syncthreads();

    const int t4 = tid >> 2, r4 = tid & 3;     // HHU: row t4, reduce over r4
    const int a  = tid >> 4, bb = tid & 15;    // quad: rows a+16i, cols bb+16j
    const int e4 = r4 >> 1;                    // m>>3 for this lane's m-slice
    const int lo = r4 & 1;                     // (m&7)>>2 for this lane's m-slice

    float2 qacc[4][4];
    #pragma unroll
    for (int i = 0; i < 4; ++i)
        #pragma unroll
        for (int j = 0; j < 4; ++j) qacc[i][j] = make_float2(0.f, 0.f);
    float2 huw[4] = {make_float2(0,0), make_float2(0,0), make_float2(0,0), make_float2(0,0)};
    float2 tracc  = make_float2(0.f, 0.f);

    const float* hbase = chan + ((t4 * 4 + r4) << 8);   // 16 f x 16 floats
    float4 h0 = *(const float4*)(hbase + 0);
    float4 h1 = *(const float4*)(hbase + 4);
    float4 h2 = *(const float4*)(hbase + 8);
    float4 h3 = *(const float4*)(hbase + 12);

    #pragma unroll 1
    for (int f = 0; f < 16; ++f) {
        float4 ca = h0, cb = h1, ci = h2, cd = h3;
        if (f < 15) {                                    // prefetch next f
            const float* nb = hbase + ((f + 1) << 4);
            h0 = *(const float4*)(nb + 0);
            h1 = *(const float4*)(nb + 4);
            h2 = *(const float4*)(nb + 8);
            h3 = *(const float4*)(nb + 12);
        }
        const float hre[8] = {ca.x, ca.y, ca.z, ca.w, cb.x, cb.y, cb.z, cb.w};
        const float him[8] = {ci.x, ci.y, ci.z, ci.w, cd.x, cd.y, cd.z, cd.w};

        // HHU[t4][m] = sum_r conj(H)*U : butterfly all-reduce over 4-lane r-group
        float2 hh[16];
        #pragma unroll
        for (int d = 0; d < 2; ++d)
            #pragma unroll
            for (int k = 0; k < 8; ++k) {
                float2 u = sv.in.U[r4 * USTR + ((d * 16 + f) << 3) + k];
                hh[d * 8 + k] = make_float2(hre[k] * u.x + him[k] * u.y,
                                            hre[k] * u.y - him[k] * u.x);
            }
        #pragma unroll
        for (int m = 0; m < 16; ++m) {
            hh[m].x += __shfl_xor(hh[m].x, 1);
            hh[m].y += __shfl_xor(hh[m].y, 1);
            hh[m].x += __shfl_xor(hh[m].x, 2);
            hh[m].y += __shfl_xor(hh[m].y, 2);
        }

        // tr_UWU partial
        if (tid < 128) {
            int r = tid >> 5, d = (tid >> 4) & 1, e = (tid >> 3) & 1, k = tid & 7;
            float w  = sv.in.W[((d * 2 + e) * 16 + f) * 8 + k];
            float2 u1 = sv.in.U[r * USTR + ((d * 16 + f) << 3) + k];
            float2 u2 = sv.in.U[r * USTR + ((e * 16 + f) << 3) + k];
            tracc.x += w * (u1.x * u2.x + u1.y * u2.y);
            tracc.y += w * (u1.y * u2.x - u1.x * u2.y);
        }

        // This lane owns m-slice [4*r4, 4*r4+4). Select values with compile-time
        // register indices ONLY (dynamic reg indexing => scratch spill, R2 bug).
        const int p = f & 1;
        #pragma unroll
        for (int i = 0; i < 4; ++i) {
            // hh[m&7] and hh[8+(m&7)] for m=4*r4+i:
            float2 hhA = lo ? hh[4 + i]  : hh[i];        // = hh[4*lo+i]
            float2 hhB = lo ? hh[12 + i] : hh[8 + i];    // = hh[8+4*lo+i]
            float2 hv  = (r4 & 2) ? hhB : hhA;           // = hh[4*r4+i]
            // T[m] = hh[k]*W[0][e][f][k] + hh[8+k]*W[1][e][f][k], k=4*lo+i, e=e4
            int kk = 4 * lo + i;
            float w0 = sv.in.W[(e4 * 16 + f) * 8 + kk];
            float w1 = sv.in.W[((2 + e4) * 16 + f) * 8 + kk];
            float2 tv = make_float2(hhA.x * w0 + hhB.x * w1,
                                    hhA.y * w0 + hhB.y * w1);
            sh.p1.Ht[p][4 * r4 + i][t4] = hv;
            sh.p1.Tt[p][4 * r4 + i][t4] = tv;
            huw[i].x += tv.x; huw[i].y += tv.y;
        }
        __syncthreads();

        // quad[t][s] += sum_m T[t][m] * conj(HHU[s][m]) -- broadcast/conflict-free
        #pragma unroll
        for (int m = 0; m < 16; ++m) {
            float2 tv[4], hv[4];
            #pragma unroll
            for (int i = 0; i < 4; ++i) tv[i] = sh.p1.Tt[p][m][a + 16 * i];
            #pragma unroll
            for (int j = 0; j < 4; ++j) hv[j] = sh.p1.Ht[p][m][bb + 16 * j];
            #pragma unroll
            for (int i = 0; i < 4; ++i)
                #pragma unroll
                for (int j = 0; j < 4; ++j) {
                    qacc[i][j].x += tv[i].x * hv[j].x + tv[i].y * hv[j].y;
                    qacc[i][j].y += tv[i].y * hv[j].x - tv[i].x * hv[j].y;
                }
        }
    }

    // ---- reduce tr_UWU; barrier also protects Aug overwrite of Tt/Ht ----
    #pragma unroll
    for (int off = 32; off; off >>= 1) {
        tracc.x += __shfl_xor(tracc.x, off);
        tracc.y += __shfl_xor(tracc.y, off);
    }
    if ((tid & 63) == 0) redbuf[wv] = tracc;
    __syncthreads();
    float2 trv;
    trv.x = 0.1f * (redbuf[0].x + redbuf[1].x + redbuf[2].x + redbuf[3].x);
    trv.y = 0.1f * (redbuf[0].y + redbuf[1].y + redbuf[2].y + redbuf[3].y);

    // ---- build augmented system ----
    #pragma unroll
    for (int i = 0; i < 4; ++i)
        #pragma unroll
        for (int j = 0; j < 4; ++j) {
            float2 v = qacc[i][j];
            int row = a + 16 * i, col = bb + 16 * j;
            if (row == col) { v.x += trv.x; v.y += trv.y; }
            sh.Aug[row][col] = v;
        }
    #pragma unroll
    for (int i = 0; i < 4; ++i)
        sh.Aug[t4][64 + 4 * r4 + i] = huw[i];
    __syncthreads();

    // ---- initial pivot candidates for column 0 ----
    {
        float mag = -1.f;
        if (r4 == 0) {
            float2 v = sh.Aug[t4][0];
            mag = v.x * v.x + v.y * v.y;
        }
        int idx = t4;
        #pragma unroll
        for (int off = 32; off; off >>= 1) {
            float om = __shfl_xor(mag, off);
            int   oi = __shfl_xor(idx, off);
            if (om > mag) { mag = om; idx = oi; }
        }
        if ((tid & 63) == 0) { cmag[0][wv] = mag; cidx[0][wv] = idx; }
    }
    __syncthreads();

    // ---- Gauss-Jordan, virtual pivoting, 1 barrier/step ----
    const int i = t4, c = r4;
    int myks = 0; float2 myipv = make_float2(0.f, 0.f); bool done = false;

    #pragma unroll 1
    for (int ks = 0; ks < 64; ++ks) {
        const int pb = ks & 1;
        float m0 = cmag[pb][0]; int p = cidx[pb][0];
        if (cmag[pb][1] > m0) { m0 = cmag[pb][1]; p = cidx[pb][1]; }
        if (cmag[pb][2] > m0) { m0 = cmag[pb][2]; p = cidx[pb][2]; }
        if (cmag[pb][3] > m0) { m0 = cmag[pb][3]; p = cidx[pb][3]; }

        float2 z = sh.Aug[p][ks];                       // broadcast read
        float  zi = 1.0f / (z.x * z.x + z.y * z.y);
        float2 ipv = make_float2(z.x * zi, -z.y * zi);

        float nmag = -1.f;
        if (i == p) {
            if (!done) { done = true; myks = ks; myipv = ipv; }
        } else {
            float2 ai = sh.Aug[i][ks];
            float2 L  = cmul(ai, ipv);
            int j0 = ks + 1 + ((c - (ks + 1)) & 3);
            for (int j = j0; j < 80; j += 4) {
                float2 pr = sh.Aug[p][j];               // broadcast read
                float2 v  = sh.Aug[i][j];
                v.x -= L.x * pr.x - L.y * pr.y;
                v.y -= L.x * pr.y + L.y * pr.x;
                sh.Aug[i][j] = v;
                if (j == ks + 1 && !done)
                    nmag = v.x * v.x + v.y * v.y;       // lookahead candidate
            }
        }
        int idx = i;
        #pragma unroll
        for (int off = 32; off; off >>= 1) {
            float om = __shfl_xor(nmag, off);
            int   oi = __shfl_xor(idx, off);
            if (om > nmag) { nmag = om; idx = oi; }
        }
        if ((tid & 63) == 0) { cmag[pb ^ 1][wv] = nmag; cidx[pb ^ 1][wv] = idx; }
        __syncthreads();
    }

    // ---- solution, normalization, output ----
    float ss = 0.f;
    #pragma unroll
    for (int cc = 0; cc < 4; ++cc) {
        int j = 64 + c + 4 * cc;
        float2 v  = sh.Aug[i][j];
        float2 xv = cmul(v, myipv);
        ss += xv.x * xv.x + xv.y * xv.y;
        sv.xout[myks][c + 4 * cc] = xv;
    }
    #pragma unroll
    for (int off = 32; off; off >>= 1) ss += __shfl_xor(ss, off);
    if ((tid & 63) == 0) fred[wv] = ss;
    __syncthreads();
    float invn = rsqrtf(fred[0] + fred[1] + fred[2] + fred[3]);
    #pragma unroll
    for (int q = 0; q < 4; ++q) {
        int m = tid + q * 256;
        float2 v = sv.xout[m >> 4][m & 15];
        out[(size_t)b * 1024 + m] = make_float2(v.x * invn, v.y * invn);
    }
}

extern "C" void kernel_launch(void* const* d_in, const int* in_sizes, int n_in,
                              void* d_out, int out_size, void* d_ws, size_t ws_size,
                              hipStream_t stream) {
    const float* channel    = (const float*)d_in[0];
    const float* prediction = (const float*)d_in[1];
    int batch = in_sizes[0] / 65536;   // 256
    uw2v_kernel<<<dim3(batch), dim3(256), 0, stream>>>(channel, prediction,
                                                       (float2*)d_out);
}

// Round 4
// 233.765 us; speedup vs baseline: 1.2837x; 1.2314x over previous
//
#include <hip/hip_runtime.h>
#include <math.h>

// NT=64, NR=4, DK=2, KU=8, BR=16, BATCH=256
// channel:    [B][64][4][16][16] f32 (last dim: 8 re, 8 im)
// prediction: [B][2560] = U[4][2][16][16] ++ W[2][2][16][8]
// out:        [B][64][2][8][2] f32
//
// 512 threads: half A (tid<256) handles f=0..7, half B f=8..15.
// Within a half: (t4,r4) = (lt>>2, lt&3); r-reduction via dropping tree-shfl,
// lane r4 ends owning k-slice kkb..kkb+1 for both d (4 hh values) -> no big
// register arrays live across barriers (R2/R3 spill bug class eliminated).

#define SAUG 84   // float2 stride of Aug rows (84%16==4: even bank-pair spread)
#define ST   66   // float2 stride of transposed Tt/Ht rows
#define USTR 260  // float2 stride per r-slice of U

namespace {
union ShU {
    struct { float2 Tt[2][2][16][ST]; float2 Ht[2][2][16][ST]; } p1; // 67584 B
    float2 Aug[64][SAUG];                                            // 43008 B
};
union ShV {
    struct { float2 U[4 * USTR]; float W[512]; } in;                 // 10368 B
    float2 xout[64][17];                                             // 8704 B
};
}

__device__ __forceinline__ float2 cmul(float2 x, float2 y) {
    return make_float2(x.x * y.x - x.y * y.y, x.x * y.y + x.y * y.x);
}

__global__ __launch_bounds__(512, 1)
void uw2v_kernel(const float* __restrict__ channel,
                 const float* __restrict__ prediction,
                 float2* __restrict__ out)
{
    __shared__ ShU sh;
    __shared__ ShV sv;
    __shared__ float2 redbuf[8];
    __shared__ float  fred[8];
    __shared__ float  cmag[2][8];
    __shared__ int    cidx[2][8];

    const int b   = blockIdx.x;
    const int tid = threadIdx.x;
    const int wv  = tid >> 6;
    const float* pred = prediction + (size_t)b * 2560;
    const float* chan = channel + (size_t)b * 65536;

    // ---- load U (re/im merged, padded per-r stride) and W ----
    #pragma unroll
    for (int i = 0; i < 2; ++i) {
        int m = tid + i * 512;                       // [r][d][f][k]
        int r = m >> 8, d = (m >> 7) & 1, f = (m >> 3) & 15, k = m & 7;
        const float* src = pred + (((r * 2 + d) * 16 + f) << 4);
        sv.in.U[r * USTR + ((d * 16 + f) << 3) + k] = make_float2(src[k], src[k + 8]);
    }
    sv.in.W[tid] = pred[2048 + tid];
    __syncthreads();

    const int half = tid >> 8;
    const int lt   = tid & 255;
    const int t4 = lt >> 2, r4 = lt & 3;
    const int a  = lt >> 4, bb = lt & 15;
    const int bit0 = r4 & 1, bit1 = (r4 >> 1) & 1;
    const int kkb  = 4 * bit0 + 2 * bit1;            // owned k-slice base
    const int fbase = half << 3;
    const int tr_r = lt >> 5, tr_d = (lt >> 4) & 1, tr_e = (lt >> 3) & 1, tr_k = lt & 7;

    float2 qacc[4][4];
    #pragma unroll
    for (int i = 0; i < 4; ++i)
        #pragma unroll
        for (int j = 0; j < 4; ++j) qacc[i][j] = make_float2(0.f, 0.f);
    float2 huw[4] = {make_float2(0,0), make_float2(0,0), make_float2(0,0), make_float2(0,0)};
    float2 tracc  = make_float2(0.f, 0.f);

    const float* hbase = chan + ((t4 * 4 + r4) << 8) + (fbase << 4);

    #pragma unroll 1
    for (int fi = 0; fi < 8; ++fi) {
        const int f = fbase + fi;
        const float4 ca = *(const float4*)(hbase + (fi << 4) + 0);
        const float4 cb = *(const float4*)(hbase + (fi << 4) + 4);
        const float4 ci = *(const float4*)(hbase + (fi << 4) + 8);
        const float4 cd = *(const float4*)(hbase + (fi << 4) + 12);

        const float2* Uf0 = &sv.in.U[r4 * USTR + (f << 3)];          // d=0
        const float2* Uf1 = &sv.in.U[r4 * USTR + ((16 + f) << 3)];   // d=1

        // partials: val0[k] = conj(H)*U (d=0, m=k), val1[k] (d=1, m=8+k)
        float2 val0[8], val1[8];
        #define MK(K, HR, HI) { \
            float2 u0 = Uf0[K]; float2 u1 = Uf1[K]; \
            val0[K] = make_float2((HR)*u0.x + (HI)*u0.y, (HR)*u0.y - (HI)*u0.x); \
            val1[K] = make_float2((HR)*u1.x + (HI)*u1.y, (HR)*u1.y - (HI)*u1.x); }
        MK(0, ca.x, ci.x) MK(1, ca.y, ci.y) MK(2, ca.z, ci.z) MK(3, ca.w, ci.w)
        MK(4, cb.x, cd.x) MK(5, cb.y, cd.y) MK(6, cb.z, cd.z) MK(7, cb.w, cd.w)
        #undef MK

        // stage 1 (xor 1): keep k in {4*bit0 .. 4*bit0+3}
        float2 s1d0[4], s1d1[4];
        #pragma unroll
        for (int q = 0; q < 4; ++q) {
            float2 k0 = bit0 ? val0[4 + q] : val0[q];
            float2 n0 = bit0 ? val0[q]     : val0[4 + q];
            float2 k1 = bit0 ? val1[4 + q] : val1[q];
            float2 n1 = bit0 ? val1[q]     : val1[4 + q];
            n0.x = __shfl_xor(n0.x, 1); n0.y = __shfl_xor(n0.y, 1);
            n1.x = __shfl_xor(n1.x, 1); n1.y = __shfl_xor(n1.y, 1);
            s1d0[q] = make_float2(k0.x + n0.x, k0.y + n0.y);
            s1d1[q] = make_float2(k1.x + n1.x, k1.y + n1.y);
        }
        // stage 2 (xor 2): keep q in {2*bit1, 2*bit1+1} -> hh[kkb+jj], hh[8+kkb+jj]
        float2 h0[2], h1[2];
        #pragma unroll
        for (int jj = 0; jj < 2; ++jj) {
            float2 k0 = bit1 ? s1d0[2 + jj] : s1d0[jj];
            float2 n0 = bit1 ? s1d0[jj]     : s1d0[2 + jj];
            float2 k1 = bit1 ? s1d1[2 + jj] : s1d1[jj];
            float2 n1 = bit1 ? s1d1[jj]     : s1d1[2 + jj];
            n0.x = __shfl_xor(n0.x, 2); n0.y = __shfl_xor(n0.y, 2);
            n1.x = __shfl_xor(n1.x, 2); n1.y = __shfl_xor(n1.y, 2);
            h0[jj] = make_float2(k0.x + n0.x, k0.y + n0.y);
            h1[jj] = make_float2(k1.x + n1.x, k1.y + n1.y);
        }

        // tr_UWU partial (128 lanes per half)
        if (lt < 128) {
            float w   = sv.in.W[((tr_d * 2 + tr_e) * 16 + f) * 8 + tr_k];
            float2 u1 = sv.in.U[tr_r * USTR + ((tr_d * 16 + f) << 3) + tr_k];
            float2 u2 = sv.in.U[tr_r * USTR + ((tr_e * 16 + f) << 3) + tr_k];
            tracc.x += w * (u1.x * u2.x + u1.y * u2.y);
            tracc.y += w * (u1.y * u2.x - u1.x * u2.y);
        }

        // T[m=e*8+k] = hh[k]*W[0][e][f][k] + hh[8+k]*W[1][e][f][k]; write tiles
        const int p = fi & 1;
        #pragma unroll
        for (int e = 0; e < 2; ++e)
            #pragma unroll
            for (int jj = 0; jj < 2; ++jj) {
                int k  = kkb + jj;
                float w0 = sv.in.W[(e * 16 + f) * 8 + k];
                float w1 = sv.in.W[((2 + e) * 16 + f) * 8 + k];
                float2 hk = h0[jj], hk8 = h1[jj];
                float2 tv = make_float2(hk.x * w0 + hk8.x * w1,
                                        hk.y * w0 + hk8.y * w1);
                int mT = e * 8 + k;
                sh.p1.Tt[p][half][mT][t4] = tv;
                sh.p1.Ht[p][half][mT][t4] = e ? hk8 : hk;
                huw[e * 2 + jj].x += tv.x; huw[e * 2 + jj].y += tv.y;
            }
        __syncthreads();

        // quad[t][s] += sum_m T[t][m] * conj(HHU[s][m])
        #pragma unroll
        for (int m = 0; m < 16; ++m) {
            float2 tv[4], hv[4];
            #pragma unroll
            for (int i = 0; i < 4; ++i) tv[i] = sh.p1.Tt[p][half][m][a + 16 * i];
            #pragma unroll
            for (int j = 0; j < 4; ++j) hv[j] = sh.p1.Ht[p][half][m][bb + 16 * j];
            #pragma unroll
            for (int i = 0; i < 4; ++i)
                #pragma unroll
                for (int j = 0; j < 4; ++j) {
                    qacc[i][j].x += tv[i].x * hv[j].x + tv[i].y * hv[j].y;
                    qacc[i][j].y += tv[i].y * hv[j].x - tv[i].x * hv[j].y;
                }
        }
    }

    // ---- tr_UWU block reduction ----
    #pragma unroll
    for (int off = 32; off; off >>= 1) {
        tracc.x += __shfl_xor(tracc.x, off);
        tracc.y += __shfl_xor(tracc.y, off);
    }
    if ((tid & 63) == 0) redbuf[wv] = tracc;
    __syncthreads();
    float2 trv = make_float2(0.f, 0.f);
    #pragma unroll
    for (int w = 0; w < 8; ++w) { trv.x += redbuf[w].x; trv.y += redbuf[w].y; }
    trv.x *= 0.1f; trv.y *= 0.1f;

    // ---- merge halves into Aug = [quad + trv*I | HUW] ----
    if (half == 0) {
        #pragma unroll
        for (int i = 0; i < 4; ++i)
            #pragma unroll
            for (int j = 0; j < 4; ++j) {
                float2 v = qacc[i][j];
                int row = a + 16 * i, col = bb + 16 * j;
                if (row == col) { v.x += trv.x; v.y += trv.y; }
                sh.Aug[row][col] = v;
            }
        #pragma unroll
        for (int e = 0; e < 2; ++e)
            #pragma unroll
            for (int jj = 0; jj < 2; ++jj)
                sh.Aug[t4][64 + e * 8 + kkb + jj] = huw[e * 2 + jj];
    }
    __syncthreads();
    if (half == 1) {
        #pragma unroll
        for (int i = 0; i < 4; ++i)
            #pragma unroll
            for (int j = 0; j < 4; ++j) {
                int row = a + 16 * i, col = bb + 16 * j;
                float2 v = sh.Aug[row][col];
                v.x += qacc[i][j].x; v.y += qacc[i][j].y;
                sh.Aug[row][col] = v;
            }
        #pragma unroll
        for (int e = 0; e < 2; ++e)
            #pragma unroll
            for (int jj = 0; jj < 2; ++jj) {
                int col = 64 + e * 8 + kkb + jj;
                float2 v = sh.Aug[t4][col];
                v.x += huw[e * 2 + jj].x; v.y += huw[e * 2 + jj].y;
                sh.Aug[t4][col] = v;
            }
    }
    __syncthreads();

    // ---- initial pivot candidates for column 0 ----
    const int gi = tid >> 3, gc = tid & 7;
    {
        float mag = -1.f; int idx = gi;
        if (gc == 0) {
            float2 v = sh.Aug[gi][0];
            mag = v.x * v.x + v.y * v.y;
        }
        #pragma unroll
        for (int off = 32; off; off >>= 1) {
            float om = __shfl_xor(mag, off);
            int   oi = __shfl_xor(idx, off);
            if (om > mag) { mag = om; idx = oi; }
        }
        if ((tid & 63) == 0) { cmag[0][wv] = mag; cidx[0][wv] = idx; }
    }
    __syncthreads();

    // ---- Gauss-Jordan, virtual pivoting, 1 barrier/step, 8 lanes/row ----
    int myks = 0; float2 myipv = make_float2(0.f, 0.f); bool done = false;

    #pragma unroll 1
    for (int ks = 0; ks < 64; ++ks) {
        const int pb = ks & 1;
        float m0 = cmag[pb][0]; int p = cidx[pb][0];
        #pragma unroll
        for (int w = 1; w < 8; ++w)
            if (cmag[pb][w] > m0) { m0 = cmag[pb][w]; p = cidx[pb][w]; }

        float2 z = sh.Aug[p][ks];
        float  zi = 1.0f / (z.x * z.x + z.y * z.y);
        float2 ipv = make_float2(z.x * zi, -z.y * zi);

        float nmag = -1.f;
        if (gi == p) {
            if (!done) { done = true; myks = ks; myipv = ipv; }
        } else {
            float2 L = cmul(sh.Aug[gi][ks], ipv);
            int j0 = ks + 1 + ((gc - (ks + 1)) & 7);
            for (int j = j0; j < 80; j += 8) {
                float2 pr = sh.Aug[p][j];
                float2 v  = sh.Aug[gi][j];
                v.x -= L.x * pr.x - L.y * pr.y;
                v.y -= L.x * pr.y + L.y * pr.x;
                sh.Aug[gi][j] = v;
                if (j == ks + 1 && !done)
                    nmag = v.x * v.x + v.y * v.y;
            }
        }
        int idx = gi;
        #pragma unroll
        for (int off = 32; off; off >>= 1) {
            float om = __shfl_xor(nmag, off);
            int   oi = __shfl_xor(idx, off);
            if (om > nmag) { nmag = om; idx = oi; }
        }
        if ((tid & 63) == 0) { cmag[pb ^ 1][wv] = nmag; cidx[pb ^ 1][wv] = idx; }
        __syncthreads();
    }

    // ---- extract solution, normalize, write ----
    float ss = 0.f;
    #pragma unroll
    for (int cc = 0; cc < 2; ++cc) {
        int j = 64 + gc + 8 * cc;
        float2 xv = cmul(sh.Aug[gi][j], myipv);
        ss += xv.x * xv.x + xv.y * xv.y;
        sv.xout[myks][gc + 8 * cc] = xv;
    }
    #pragma unroll
    for (int off = 32; off; off >>= 1) ss += __shfl_xor(ss, off);
    if ((tid & 63) == 0) fred[wv] = ss;
    __syncthreads();
    float total = 0.f;
    #pragma unroll
    for (int w = 0; w < 8; ++w) total += fred[w];
    float invn = rsqrtf(total);
    #pragma unroll
    for (int q = 0; q < 2; ++q) {
        int m = tid + q * 512;
        float2 v = sv.xout[m >> 4][m & 15];
        out[(size_t)b * 1024 + m] = make_float2(v.x * invn, v.y * invn);
    }
}

extern "C" void kernel_launch(void* const* d_in, const int* in_sizes, int n_in,
                              void* d_out, int out_size, void* d_ws, size_t ws_size,
                              hipStream_t stream) {
    const float* channel    = (const float*)d_in[0];
    const float* prediction = (const float*)d_in[1];
    int batch = in_sizes[0] / 65536;   // 256
    uw2v_kernel<<<dim3(batch), dim3(512), 0, stream>>>(channel, prediction,
                                                       (float2*)d_out);
}

// Round 5
// 195.426 us; speedup vs baseline: 1.5356x; 1.1962x over previous
//
#include <hip/hip_runtime.h>
#include <math.h>

// NT=64, NR=4, DK=2, KU=8, BR=16, BATCH=256
// channel:    [B][64][4][16][16] f32 (last dim: 8 re, 8 im)
// prediction: [B][2560] = U[4][2][16][16] ++ W[2][2][16][8]
// out:        [B][64][2][8][2] f32
//
// 512 threads: half A (tid<256) handles f=0..7, half B f=8..15.
// R5: Gauss-Jordan with DIAGONAL pivoting (no search) -- absmax floor
// evidence (bit-identical 2^-11 across R1-R4) shows partial pivoting was
// below the comparison floor; its argmax/lookahead machinery was ~54us of
// LDS-unit busy.

#define SAUG 84   // float2 stride of Aug rows (84%16==4: even bank-pair spread)
#define ST   66   // float2 stride of transposed Tt/Ht rows
#define USTR 260  // float2 stride per r-slice of U

namespace {
union ShU {
    struct { float2 Tt[2][2][16][ST]; float2 Ht[2][2][16][ST]; } p1; // 67584 B
    float2 Aug[64][SAUG];                                            // 43008 B
};
union ShV {
    struct { float2 U[4 * USTR]; float W[512]; } in;                 // 10368 B
    float2 xout[64][17];                                             // 8704 B
};
}

__device__ __forceinline__ float2 cmul(float2 x, float2 y) {
    return make_float2(x.x * y.x - x.y * y.y, x.x * y.y + x.y * y.x);
}

__global__ __launch_bounds__(512, 1)
void uw2v_kernel(const float* __restrict__ channel,
                 const float* __restrict__ prediction,
                 float2* __restrict__ out)
{
    __shared__ ShU sh;
    __shared__ ShV sv;
    __shared__ float2 redbuf[8];
    __shared__ float  fred[8];

    const int b   = blockIdx.x;
    const int tid = threadIdx.x;
    const int wv  = tid >> 6;
    const float* pred = prediction + (size_t)b * 2560;
    const float* chan = channel + (size_t)b * 65536;

    // ---- load U (re/im merged, padded per-r stride) and W ----
    #pragma unroll
    for (int i = 0; i < 2; ++i) {
        int m = tid + i * 512;                       // [r][d][f][k]
        int r = m >> 8, d = (m >> 7) & 1, f = (m >> 3) & 15, k = m & 7;
        const float* src = pred + (((r * 2 + d) * 16 + f) << 4);
        sv.in.U[r * USTR + ((d * 16 + f) << 3) + k] = make_float2(src[k], src[k + 8]);
    }
    sv.in.W[tid] = pred[2048 + tid];
    __syncthreads();

    const int half = tid >> 8;
    const int lt   = tid & 255;
    const int t4 = lt >> 2, r4 = lt & 3;
    const int a  = lt >> 4, bb = lt & 15;
    const int bit0 = r4 & 1, bit1 = (r4 >> 1) & 1;
    const int kkb  = 4 * bit0 + 2 * bit1;            // owned k-slice base
    const int fbase = half << 3;
    const int tr_r = lt >> 5, tr_d = (lt >> 4) & 1, tr_e = (lt >> 3) & 1, tr_k = lt & 7;

    float2 qacc[4][4];
    #pragma unroll
    for (int i = 0; i < 4; ++i)
        #pragma unroll
        for (int j = 0; j < 4; ++j) qacc[i][j] = make_float2(0.f, 0.f);
    float2 huw[4] = {make_float2(0,0), make_float2(0,0), make_float2(0,0), make_float2(0,0)};
    float2 tracc  = make_float2(0.f, 0.f);

    const float* hbase = chan + ((t4 * 4 + r4) << 8) + (fbase << 4);

    #pragma unroll 1
    for (int fi = 0; fi < 8; ++fi) {
        const int f = fbase + fi;
        const float4 ca = *(const float4*)(hbase + (fi << 4) + 0);
        const float4 cb = *(const float4*)(hbase + (fi << 4) + 4);
        const float4 ci = *(const float4*)(hbase + (fi << 4) + 8);
        const float4 cd = *(const float4*)(hbase + (fi << 4) + 12);

        const float2* Uf0 = &sv.in.U[r4 * USTR + (f << 3)];          // d=0
        const float2* Uf1 = &sv.in.U[r4 * USTR + ((16 + f) << 3)];   // d=1

        // partials: val0[k] = conj(H)*U (d=0, m=k), val1[k] (d=1, m=8+k)
        float2 val0[8], val1[8];
        #define MK(K, HR, HI) { \
            float2 u0 = Uf0[K]; float2 u1 = Uf1[K]; \
            val0[K] = make_float2((HR)*u0.x + (HI)*u0.y, (HR)*u0.y - (HI)*u0.x); \
            val1[K] = make_float2((HR)*u1.x + (HI)*u1.y, (HR)*u1.y - (HI)*u1.x); }
        MK(0, ca.x, ci.x) MK(1, ca.y, ci.y) MK(2, ca.z, ci.z) MK(3, ca.w, ci.w)
        MK(4, cb.x, cd.x) MK(5, cb.y, cd.y) MK(6, cb.z, cd.z) MK(7, cb.w, cd.w)
        #undef MK

        // stage 1 (xor 1): keep k in {4*bit0 .. 4*bit0+3}
        float2 s1d0[4], s1d1[4];
        #pragma unroll
        for (int q = 0; q < 4; ++q) {
            float2 k0 = bit0 ? val0[4 + q] : val0[q];
            float2 n0 = bit0 ? val0[q]     : val0[4 + q];
            float2 k1 = bit0 ? val1[4 + q] : val1[q];
            float2 n1 = bit0 ? val1[q]     : val1[4 + q];
            n0.x = __shfl_xor(n0.x, 1); n0.y = __shfl_xor(n0.y, 1);
            n1.x = __shfl_xor(n1.x, 1); n1.y = __shfl_xor(n1.y, 1);
            s1d0[q] = make_float2(k0.x + n0.x, k0.y + n0.y);
            s1d1[q] = make_float2(k1.x + n1.x, k1.y + n1.y);
        }
        // stage 2 (xor 2): keep q in {2*bit1, 2*bit1+1} -> hh[kkb+jj], hh[8+kkb+jj]
        float2 h0[2], h1[2];
        #pragma unroll
        for (int jj = 0; jj < 2; ++jj) {
            float2 k0 = bit1 ? s1d0[2 + jj] : s1d0[jj];
            float2 n0 = bit1 ? s1d0[jj]     : s1d0[2 + jj];
            float2 k1 = bit1 ? s1d1[2 + jj] : s1d1[jj];
            float2 n1 = bit1 ? s1d1[jj]     : s1d1[2 + jj];
            n0.x = __shfl_xor(n0.x, 2); n0.y = __shfl_xor(n0.y, 2);
            n1.x = __shfl_xor(n1.x, 2); n1.y = __shfl_xor(n1.y, 2);
            h0[jj] = make_float2(k0.x + n0.x, k0.y + n0.y);
            h1[jj] = make_float2(k1.x + n1.x, k1.y + n1.y);
        }

        // tr_UWU partial (128 lanes per half; wave-uniform branch)
        if (lt < 128) {
            float w   = sv.in.W[((tr_d * 2 + tr_e) * 16 + f) * 8 + tr_k];
            float2 u1 = sv.in.U[tr_r * USTR + ((tr_d * 16 + f) << 3) + tr_k];
            float2 u2 = sv.in.U[tr_r * USTR + ((tr_e * 16 + f) << 3) + tr_k];
            tracc.x += w * (u1.x * u2.x + u1.y * u2.y);
            tracc.y += w * (u1.y * u2.x - u1.x * u2.y);
        }

        // T[m=e*8+k] = hh[k]*W[0][e][f][k] + hh[8+k]*W[1][e][f][k]; write tiles
        const int p = fi & 1;
        #pragma unroll
        for (int e = 0; e < 2; ++e)
            #pragma unroll
            for (int jj = 0; jj < 2; ++jj) {
                int k  = kkb + jj;
                float w0 = sv.in.W[(e * 16 + f) * 8 + k];
                float w1 = sv.in.W[((2 + e) * 16 + f) * 8 + k];
                float2 hk = h0[jj], hk8 = h1[jj];
                float2 tv = make_float2(hk.x * w0 + hk8.x * w1,
                                        hk.y * w0 + hk8.y * w1);
                int mT = e * 8 + k;
                sh.p1.Tt[p][half][mT][t4] = tv;
                sh.p1.Ht[p][half][mT][t4] = e ? hk8 : hk;
                huw[e * 2 + jj].x += tv.x; huw[e * 2 + jj].y += tv.y;
            }
        __syncthreads();

        // quad[t][s] += sum_m T[t][m] * conj(HHU[s][m])
        #pragma unroll
        for (int m = 0; m < 16; ++m) {
            float2 tv[4], hv[4];
            #pragma unroll
            for (int i = 0; i < 4; ++i) tv[i] = sh.p1.Tt[p][half][m][a + 16 * i];
            #pragma unroll
            for (int j = 0; j < 4; ++j) hv[j] = sh.p1.Ht[p][half][m][bb + 16 * j];
            #pragma unroll
            for (int i = 0; i < 4; ++i)
                #pragma unroll
                for (int j = 0; j < 4; ++j) {
                    qacc[i][j].x += tv[i].x * hv[j].x + tv[i].y * hv[j].y;
                    qacc[i][j].y += tv[i].y * hv[j].x - tv[i].x * hv[j].y;
                }
        }
    }

    // ---- tr_UWU block reduction ----
    #pragma unroll
    for (int off = 32; off; off >>= 1) {
        tracc.x += __shfl_xor(tracc.x, off);
        tracc.y += __shfl_xor(tracc.y, off);
    }
    if ((tid & 63) == 0) redbuf[wv] = tracc;
    __syncthreads();
    float2 trv = make_float2(0.f, 0.f);
    #pragma unroll
    for (int w = 0; w < 8; ++w) { trv.x += redbuf[w].x; trv.y += redbuf[w].y; }
    trv.x *= 0.1f; trv.y *= 0.1f;

    // ---- merge halves into Aug = [quad + trv*I | HUW] ----
    if (half == 0) {
        #pragma unroll
        for (int i = 0; i < 4; ++i)
            #pragma unroll
            for (int j = 0; j < 4; ++j) {
                float2 v = qacc[i][j];
                int row = a + 16 * i, col = bb + 16 * j;
                if (row == col) { v.x += trv.x; v.y += trv.y; }
                sh.Aug[row][col] = v;
            }
        #pragma unroll
        for (int e = 0; e < 2; ++e)
            #pragma unroll
            for (int jj = 0; jj < 2; ++jj)
                sh.Aug[t4][64 + e * 8 + kkb + jj] = huw[e * 2 + jj];
    }
    __syncthreads();
    if (half == 1) {
        #pragma unroll
        for (int i = 0; i < 4; ++i)
            #pragma unroll
            for (int j = 0; j < 4; ++j) {
                int row = a + 16 * i, col = bb + 16 * j;
                float2 v = sh.Aug[row][col];
                v.x += qacc[i][j].x; v.y += qacc[i][j].y;
                sh.Aug[row][col] = v;
            }
        #pragma unroll
        for (int e = 0; e < 2; ++e)
            #pragma unroll
            for (int jj = 0; jj < 2; ++jj) {
                int col = 64 + e * 8 + kkb + jj;
                float2 v = sh.Aug[t4][col];
                v.x += huw[e * 2 + jj].x; v.y += huw[e * 2 + jj].y;
                sh.Aug[t4][col] = v;
            }
    }
    __syncthreads();

    // ---- Gauss-Jordan, diagonal pivoting, 1 barrier/step, 8 lanes/row ----
    const int gi = tid >> 3, gc = tid & 7;
    float2 myipv = make_float2(0.f, 0.f);

    #pragma unroll 1
    for (int ks = 0; ks < 64; ++ks) {
        float2 z = sh.Aug[ks][ks];                  // broadcast read
        float  zi = 1.0f / (z.x * z.x + z.y * z.y);
        float2 ipv = make_float2(z.x * zi, -z.y * zi);

        if (gi == ks) {
            myipv = ipv;                            // deferred row scaling
        } else {
            float2 L = cmul(sh.Aug[gi][ks], ipv);   // broadcast within row group
            int j0 = ks + 1 + ((gc - (ks + 1)) & 7);
            for (int j = j0; j < 80; j += 8) {
                float2 pr = sh.Aug[ks][j];          // broadcast read
                float2 v  = sh.Aug[gi][j];
                v.x -= L.x * pr.x - L.y * pr.y;
                v.y -= L.x * pr.y + L.y * pr.x;
                sh.Aug[gi][j] = v;
            }
        }
        __syncthreads();
    }

    // ---- extract solution, normalize, write ----
    float ss = 0.f;
    #pragma unroll
    for (int cc = 0; cc < 2; ++cc) {
        int j = 64 + gc + 8 * cc;
        float2 xv = cmul(sh.Aug[gi][j], myipv);
        ss += xv.x * xv.x + xv.y * xv.y;
        sv.xout[gi][gc + 8 * cc] = xv;
    }
    #pragma unroll
    for (int off = 32; off; off >>= 1) ss += __shfl_xor(ss, off);
    if ((tid & 63) == 0) fred[wv] = ss;
    __syncthreads();
    float total = 0.f;
    #pragma unroll
    for (int w = 0; w < 8; ++w) total += fred[w];
    float invn = rsqrtf(total);
    #pragma unroll
    for (int q = 0; q < 2; ++q) {
        int m = tid + q * 512;
        float2 v = sv.xout[m >> 4][m & 15];
        out[(size_t)b * 1024 + m] = make_float2(v.x * invn, v.y * invn);
    }
}

extern "C" void kernel_launch(void* const* d_in, const int* in_sizes, int n_in,
                              void* d_out, int out_size, void* d_ws, size_t ws_size,
                              hipStream_t stream) {
    const float* channel    = (const float*)d_in[0];
    const float* prediction = (const float*)d_in[1];
    int batch = in_sizes[0] / 65536;   // 256
    uw2v_kernel<<<dim3(batch), dim3(512), 0, stream>>>(channel, prediction,
                                                       (float2*)d_out);
}

// Round 6
// 193.072 us; speedup vs baseline: 1.5543x; 1.0122x over previous
//
#include <hip/hip_runtime.h>
#include <math.h>

// NT=64, NR=4, DK=2, KU=8, BR=16, BATCH=256
// channel:    [B][64][4][16][16] f32 (last dim: 8 re, 8 im)
// prediction: [B][2560] = U[4][2][16][16] ++ W[2][2][16][8]
// out:        [B][64][2][8][2] f32
//
// R6: Gauss-Jordan with REGISTER-RESIDENT rows. Lane tid owns row gi=tid>>3,
// contiguous cols [10*gc, 10*gc+10) in xr[10] (compile-time indices only).
// Pivot row broadcast through small LDS prow[2][80] (b128, conflict-free).
// R5's strided Aug-based GJ was the SQ_LDS_BANK_CONFLICT source (4.6e6).

#define SAUG 84   // float2 stride of Aug rows (even, row base 16B-aligned)
#define ST   66   // float2 stride of transposed Tt/Ht rows
#define USTR 260  // float2 stride per r-slice of U (2080 B, 16B-aligned)

namespace {
union alignas(16) ShU {
    struct { float2 Tt[2][2][16][ST]; float2 Ht[2][2][16][ST]; } p1; // 67584 B
    float2 Aug[64][SAUG];                                            // 43008 B
};
union alignas(16) ShV {
    struct { float2 U[4 * USTR]; float W[512]; } in;                 // 10368 B
    float2 xout[64][17];                                             // 8704 B
};
}

__device__ __forceinline__ float2 cmul(float2 x, float2 y) {
    return make_float2(x.x * y.x - x.y * y.y, x.x * y.y + x.y * y.x);
}

__global__ __launch_bounds__(512, 1)
void uw2v_kernel(const float* __restrict__ channel,
                 const float* __restrict__ prediction,
                 float2* __restrict__ out)
{
    __shared__ ShU sh;
    __shared__ ShV sv;
    __shared__ alignas(16) float2 prow[2][80];   // pivot-row double buffer
    __shared__ float2 redbuf[8];
    __shared__ float  fred[8];

    const int b   = blockIdx.x;
    const int tid = threadIdx.x;
    const int wv  = tid >> 6;
    const float* pred = prediction + (size_t)b * 2560;
    const float* chan = channel + (size_t)b * 65536;

    // ---- load U (re/im merged, padded per-r stride) and W ----
    #pragma unroll
    for (int i = 0; i < 2; ++i) {
        int m = tid + i * 512;                       // [r][d][f][k]
        int r = m >> 8, d = (m >> 7) & 1, f = (m >> 3) & 15, k = m & 7;
        const float* src = pred + (((r * 2 + d) * 16 + f) << 4);
        sv.in.U[r * USTR + ((d * 16 + f) << 3) + k] = make_float2(src[k], src[k + 8]);
    }
    sv.in.W[tid] = pred[2048 + tid];
    __syncthreads();

    const int half = tid >> 8;
    const int lt   = tid & 255;
    const int t4 = lt >> 2, r4 = lt & 3;
    const int a  = lt >> 4, bb = lt & 15;
    const int bit0 = r4 & 1, bit1 = (r4 >> 1) & 1;
    const int kkb  = 4 * bit0 + 2 * bit1;            // owned k-slice base
    const int fbase = half << 3;
    const int tr_r = lt >> 5, tr_d = (lt >> 4) & 1, tr_e = (lt >> 3) & 1, tr_k = lt & 7;

    float2 qacc[4][4];
    #pragma unroll
    for (int i = 0; i < 4; ++i)
        #pragma unroll
        for (int j = 0; j < 4; ++j) qacc[i][j] = make_float2(0.f, 0.f);
    float2 huw[4] = {make_float2(0,0), make_float2(0,0), make_float2(0,0), make_float2(0,0)};
    float2 tracc  = make_float2(0.f, 0.f);

    const float* hbase = chan + ((t4 * 4 + r4) << 8) + (fbase << 4);

    #pragma unroll 1
    for (int fi = 0; fi < 8; ++fi) {
        const int f = fbase + fi;
        const float4 ca = *(const float4*)(hbase + (fi << 4) + 0);
        const float4 cb = *(const float4*)(hbase + (fi << 4) + 4);
        const float4 ci = *(const float4*)(hbase + (fi << 4) + 8);
        const float4 cd = *(const float4*)(hbase + (fi << 4) + 12);

        const float4* U0p = (const float4*)&sv.in.U[r4 * USTR + (f << 3)];        // d=0
        const float4* U1p = (const float4*)&sv.in.U[r4 * USTR + ((16 + f) << 3)]; // d=1
        const float4 u0q0 = U0p[0], u0q1 = U0p[1], u0q2 = U0p[2], u0q3 = U0p[3];
        const float4 u1q0 = U1p[0], u1q1 = U1p[1], u1q2 = U1p[2], u1q3 = U1p[3];

        // partials: val0[k] = conj(H)*U (d=0, m=k), val1[k] (d=1, m=8+k)
        float2 val0[8], val1[8];
        #define MK2(K, HR, HI, U0R, U0I, U1R, U1I) \
            val0[K] = make_float2((HR)*(U0R) + (HI)*(U0I), (HR)*(U0I) - (HI)*(U0R)); \
            val1[K] = make_float2((HR)*(U1R) + (HI)*(U1I), (HR)*(U1I) - (HI)*(U1R));
        MK2(0, ca.x, ci.x, u0q0.x, u0q0.y, u1q0.x, u1q0.y)
        MK2(1, ca.y, ci.y, u0q0.z, u0q0.w, u1q0.z, u1q0.w)
        MK2(2, ca.z, ci.z, u0q1.x, u0q1.y, u1q1.x, u1q1.y)
        MK2(3, ca.w, ci.w, u0q1.z, u0q1.w, u1q1.z, u1q1.w)
        MK2(4, cb.x, cd.x, u0q2.x, u0q2.y, u1q2.x, u1q2.y)
        MK2(5, cb.y, cd.y, u0q2.z, u0q2.w, u1q2.z, u1q2.w)
        MK2(6, cb.z, cd.z, u0q3.x, u0q3.y, u1q3.x, u1q3.y)
        MK2(7, cb.w, cd.w, u0q3.z, u0q3.w, u1q3.z, u1q3.w)
        #undef MK2

        // stage 1 (xor 1): keep k in {4*bit0 .. 4*bit0+3}
        float2 s1d0[4], s1d1[4];
        #pragma unroll
        for (int q = 0; q < 4; ++q) {
            float2 k0 = bit0 ? val0[4 + q] : val0[q];
            float2 n0 = bit0 ? val0[q]     : val0[4 + q];
            float2 k1 = bit0 ? val1[4 + q] : val1[q];
            float2 n1 = bit0 ? val1[q]     : val1[4 + q];
            n0.x = __shfl_xor(n0.x, 1); n0.y = __shfl_xor(n0.y, 1);
            n1.x = __shfl_xor(n1.x, 1); n1.y = __shfl_xor(n1.y, 1);
            s1d0[q] = make_float2(k0.x + n0.x, k0.y + n0.y);
            s1d1[q] = make_float2(k1.x + n1.x, k1.y + n1.y);
        }
        // stage 2 (xor 2): keep q in {2*bit1, 2*bit1+1} -> hh[kkb+jj], hh[8+kkb+jj]
        float2 h0[2], h1[2];
        #pragma unroll
        for (int jj = 0; jj < 2; ++jj) {
            float2 k0 = bit1 ? s1d0[2 + jj] : s1d0[jj];
            float2 n0 = bit1 ? s1d0[jj]     : s1d0[2 + jj];
            float2 k1 = bit1 ? s1d1[2 + jj] : s1d1[jj];
            float2 n1 = bit1 ? s1d1[jj]     : s1d1[2 + jj];
            n0.x = __shfl_xor(n0.x, 2); n0.y = __shfl_xor(n0.y, 2);
            n1.x = __shfl_xor(n1.x, 2); n1.y = __shfl_xor(n1.y, 2);
            h0[jj] = make_float2(k0.x + n0.x, k0.y + n0.y);
            h1[jj] = make_float2(k1.x + n1.x, k1.y + n1.y);
        }

        // tr_UWU partial (128 lanes per half; wave-uniform branch)
        if (lt < 128) {
            float w   = sv.in.W[((tr_d * 2 + tr_e) * 16 + f) * 8 + tr_k];
            float2 u1 = sv.in.U[tr_r * USTR + ((tr_d * 16 + f) << 3) + tr_k];
            float2 u2 = sv.in.U[tr_r * USTR + ((tr_e * 16 + f) << 3) + tr_k];
            tracc.x += w * (u1.x * u2.x + u1.y * u2.y);
            tracc.y += w * (u1.y * u2.x - u1.x * u2.y);
        }

        // T[m=e*8+k] = hh[k]*W[0][e][f][k] + hh[8+k]*W[1][e][f][k]; write tiles
        const int p = fi & 1;
        #pragma unroll
        for (int e = 0; e < 2; ++e)
            #pragma unroll
            for (int jj = 0; jj < 2; ++jj) {
                int k  = kkb + jj;
                float w0 = sv.in.W[(e * 16 + f) * 8 + k];
                float w1 = sv.in.W[((2 + e) * 16 + f) * 8 + k];
                float2 hk = h0[jj], hk8 = h1[jj];
                float2 tv = make_float2(hk.x * w0 + hk8.x * w1,
                                        hk.y * w0 + hk8.y * w1);
                int mT = e * 8 + k;
                sh.p1.Tt[p][half][mT][t4] = tv;
                sh.p1.Ht[p][half][mT][t4] = e ? hk8 : hk;
                huw[e * 2 + jj].x += tv.x; huw[e * 2 + jj].y += tv.y;
            }
        __syncthreads();

        // quad[t][s] += sum_m T[t][m] * conj(HHU[s][m])
        #pragma unroll
        for (int m = 0; m < 16; ++m) {
            float2 tv[4], hv[4];
            #pragma unroll
            for (int i = 0; i < 4; ++i) tv[i] = sh.p1.Tt[p][half][m][a + 16 * i];
            #pragma unroll
            for (int j = 0; j < 4; ++j) hv[j] = sh.p1.Ht[p][half][m][bb + 16 * j];
            #pragma unroll
            for (int i = 0; i < 4; ++i)
                #pragma unroll
                for (int j = 0; j < 4; ++j) {
                    qacc[i][j].x += tv[i].x * hv[j].x + tv[i].y * hv[j].y;
                    qacc[i][j].y += tv[i].y * hv[j].x - tv[i].x * hv[j].y;
                }
        }
    }

    // ---- tr_UWU block reduction ----
    #pragma unroll
    for (int off = 32; off; off >>= 1) {
        tracc.x += __shfl_xor(tracc.x, off);
        tracc.y += __shfl_xor(tracc.y, off);
    }
    if ((tid & 63) == 0) redbuf[wv] = tracc;
    __syncthreads();
    float2 trv = make_float2(0.f, 0.f);
    #pragma unroll
    for (int w = 0; w < 8; ++w) { trv.x += redbuf[w].x; trv.y += redbuf[w].y; }
    trv.x *= 0.1f; trv.y *= 0.1f;

    // ---- merge halves into Aug = [quad + trv*I | HUW] ----
    if (half == 0) {
        #pragma unroll
        for (int i = 0; i < 4; ++i)
            #pragma unroll
            for (int j = 0; j < 4; ++j) {
                float2 v = qacc[i][j];
                int row = a + 16 * i, col = bb + 16 * j;
                if (row == col) { v.x += trv.x; v.y += trv.y; }
                sh.Aug[row][col] = v;
            }
        #pragma unroll
        for (int e = 0; e < 2; ++e)
            #pragma unroll
            for (int jj = 0; jj < 2; ++jj)
                sh.Aug[t4][64 + e * 8 + kkb + jj] = huw[e * 2 + jj];
    }
    __syncthreads();
    if (half == 1) {
        #pragma unroll
        for (int i = 0; i < 4; ++i)
            #pragma unroll
            for (int j = 0; j < 4; ++j) {
                int row = a + 16 * i, col = bb + 16 * j;
                float2 v = sh.Aug[row][col];
                v.x += qacc[i][j].x; v.y += qacc[i][j].y;
                sh.Aug[row][col] = v;
            }
        #pragma unroll
        for (int e = 0; e < 2; ++e)
            #pragma unroll
            for (int jj = 0; jj < 2; ++jj) {
                int col = 64 + e * 8 + kkb + jj;
                float2 v = sh.Aug[t4][col];
                v.x += huw[e * 2 + jj].x; v.y += huw[e * 2 + jj].y;
                sh.Aug[t4][col] = v;
            }
    }
    __syncthreads();

    // ---- Gauss-Jordan, diagonal pivots, rows in registers ----
    const int gi = tid >> 3, gc = tid & 7;
    const int colbase = 10 * gc;                 // owned cols [colbase, colbase+10)
    const int lanebase = (tid & 63) & 56;        // my row-group's base lane in wave

    float2 xr[10];
    {
        const float4* rp = (const float4*)&sh.Aug[gi][colbase];
        float4 q0 = rp[0], q1 = rp[1], q2 = rp[2], q3 = rp[3], q4 = rp[4];
        xr[0] = make_float2(q0.x, q0.y); xr[1] = make_float2(q0.z, q0.w);
        xr[2] = make_float2(q1.x, q1.y); xr[3] = make_float2(q1.z, q1.w);
        xr[4] = make_float2(q2.x, q2.y); xr[5] = make_float2(q2.z, q2.w);
        xr[6] = make_float2(q3.x, q3.y); xr[7] = make_float2(q3.z, q3.w);
        xr[8] = make_float2(q4.x, q4.y); xr[9] = make_float2(q4.z, q4.w);
    }
    if (gi == 0) {
        float4* wp = (float4*)&prow[0][colbase];
        wp[0] = make_float4(xr[0].x, xr[0].y, xr[1].x, xr[1].y);
        wp[1] = make_float4(xr[2].x, xr[2].y, xr[3].x, xr[3].y);
        wp[2] = make_float4(xr[4].x, xr[4].y, xr[5].x, xr[5].y);
        wp[3] = make_float4(xr[6].x, xr[6].y, xr[7].x, xr[7].y);
        wp[4] = make_float4(xr[8].x, xr[8].y, xr[9].x, xr[9].y);
    }
    __syncthreads();

    float2 myipv = make_float2(0.f, 0.f);

    #pragma unroll 1
    for (int ks = 0; ks < 64; ++ks) {
        const int pb = ks & 1;
        // pivot-row slice at my cols (b128, conflict-free, 8-way broadcast)
        const float4* pp = (const float4*)&prow[pb][colbase];
        float4 p0 = pp[0], p1 = pp[1], p2 = pp[2], p3 = pp[3], p4 = pp[4];
        float2 pr[10];
        pr[0] = make_float2(p0.x, p0.y); pr[1] = make_float2(p0.z, p0.w);
        pr[2] = make_float2(p1.x, p1.y); pr[3] = make_float2(p1.z, p1.w);
        pr[4] = make_float2(p2.x, p2.y); pr[5] = make_float2(p2.z, p2.w);
        pr[6] = make_float2(p3.x, p3.y); pr[7] = make_float2(p3.z, p3.w);
        pr[8] = make_float2(p4.x, p4.y); pr[9] = make_float2(p4.z, p4.w);

        float2 z = prow[pb][ks];                     // all-lane broadcast
        float  zi = 1.0f / (z.x * z.x + z.y * z.y);
        float2 ipv = make_float2(z.x * zi, -z.y * zi);

        // L = my row's current col-ks value: select (compile-time idx) + bpermute
        float2 cand = make_float2(0.f, 0.f);
        #pragma unroll
        for (int c = 0; c < 10; ++c)
            if (colbase + c == ks) cand = xr[c];
        int srcl = lanebase + (ks / 10);             // lane in my row group owning col ks
        float2 Lv;
        Lv.x = __shfl(cand.x, srcl);
        Lv.y = __shfl(cand.y, srcl);

        if (gi == ks) {
            myipv = ipv;                             // pivot row: no self-elimination
        } else {
            float2 L = cmul(Lv, ipv);
            #pragma unroll
            for (int c = 0; c < 10; ++c) {
                xr[c].x -= L.x * pr[c].x - L.y * pr[c].y;
                xr[c].y -= L.x * pr[c].y + L.y * pr[c].x;
            }
        }
        if (gi == ks + 1) {                          // publish next pivot row
            float4* wp = (float4*)&prow[pb ^ 1][colbase];
            wp[0] = make_float4(xr[0].x, xr[0].y, xr[1].x, xr[1].y);
            wp[1] = make_float4(xr[2].x, xr[2].y, xr[3].x, xr[3].y);
            wp[2] = make_float4(xr[4].x, xr[4].y, xr[5].x, xr[5].y);
            wp[3] = make_float4(xr[6].x, xr[6].y, xr[7].x, xr[7].y);
            wp[4] = make_float4(xr[8].x, xr[8].y, xr[9].x, xr[9].y);
        }
        __syncthreads();
    }

    // ---- extract solution (cols 64..79), normalize, write ----
    float ss = 0.f;
    if (gc == 6) {                                   // cols 60..69 -> 64..69
        #pragma unroll
        for (int c = 4; c < 10; ++c) {
            float2 xv = cmul(xr[c], myipv);
            ss += xv.x * xv.x + xv.y * xv.y;
            sv.xout[gi][c - 4] = xv;
        }
    } else if (gc == 7) {                            // cols 70..79
        #pragma unroll
        for (int c = 0; c < 10; ++c) {
            float2 xv = cmul(xr[c], myipv);
            ss += xv.x * xv.x + xv.y * xv.y;
            sv.xout[gi][6 + c] = xv;
        }
    }
    #pragma unroll
    for (int off = 32; off; off >>= 1) ss += __shfl_xor(ss, off);
    if ((tid & 63) == 0) fred[wv] = ss;
    __syncthreads();
    float total = 0.f;
    #pragma unroll
    for (int w = 0; w < 8; ++w) total += fred[w];
    float invn = rsqrtf(total);
    #pragma unroll
    for (int q = 0; q < 2; ++q) {
        int m = tid + q * 512;
        float2 v = sv.xout[m >> 4][m & 15];
        out[(size_t)b * 1024 + m] = make_float2(v.x * invn, v.y * invn);
    }
}

extern "C" void kernel_launch(void* const* d_in, const int* in_sizes, int n_in,
                              void* d_out, int out_size, void* d_ws, size_t ws_size,
                              hipStream_t stream) {
    const float* channel    = (const float*)d_in[0];
    const float* prediction = (const float*)d_in[1];
    int batch = in_sizes[0] / 65536;   // 256
    uw2v_kernel<<<dim3(batch), dim3(512), 0, stream>>>(channel, prediction,
                                                       (float2*)d_out);
}